// Round 2
// baseline (7318.990 us; speedup 1.0000x reference)
//
#include <hip/hip_runtime.h>
#include <cstdint>
#include <cstddef>

// ---------------------------------------------------------------------------
// GateLoop block, round 1: bf16-storage fp32-math baseline, ~198 MiB workspace
// (round 0 crashed: 454 MiB workspace likely exceeded ws_size -> GPU fault).
//
// Pipeline:
//   1. gemm x@{Wq,Wk,Wv,Wa,Wg}; v-GEMM epilogue multiplies by stored k -> kv;
//      g-GEMM epilogue applies silu. All outputs bf16.
//   2. a_transform: a_c = sigmoid(|a|) * a/|a|  (in place, bf16)
//   3. chunked scan (3 passes, fp32 state): h_t = a_t h_{t-1} + kv_t ; y=q*h
//      pass3 stores only Re(y) (bf16); Im(y) needed only for GN stats ->
//      accumulated in registers -> fp32 atomics.
//   4. gn_gate: y = ((Re(y)-mean_re)*rstd*gn_scale + gn_bias) * g   (bf16)
//   5. gemm y@Wo -> yo ; ln1: x1 = LN(x + yo)        (x1 bf16)
//   6. gemm x1@W1 (+b1, gelu) -> h1 ; gemm h1@W2 (+b2) -> h2
//   7. ln2: out = LN(x1 + h2)  (fp32 out)
//
// Workspace (byte offsets, MDb = 32 MiB):
//   qb=0, kvb=MDb, ab=2MDb (2 planes), gb=4MDb, yb=5MDb,
//   chunk=6MDb (4 MiB), carry=+4MiB (2 MiB), stats=+2MiB (2 KiB).  ~198 MiB.
// Aliases: yo,h2 -> qb ; x1 -> kvb ; h1 -> [2MDb,6MDb).
// ---------------------------------------------------------------------------

#define EPSN 1e-6f

typedef unsigned short bf16_t;

static constexpr int    Bb     = 4;
static constexpr int    Ss     = 4096;
static constexpr int    Dd     = 1024;
static constexpr int    Ff     = 4096;
static constexpr int    Mrows  = Bb * Ss;                  // 16384
static constexpr size_t MD     = (size_t)Mrows * Dd;       // 16777216
static constexpr size_t MDb    = MD * 2;                   // bytes of one bf16 [M,D]
static constexpr int    CHUNKS = 64;
static constexpr int    CLEN   = Ss / CHUNKS;              // 64
static constexpr int    BD     = Bb * Dd;                  // 4096
static constexpr int    CBD    = CHUNKS * BD;              // 262144

__device__ __forceinline__ float b2f(bf16_t h) {
    union { unsigned int u; float f; } c; c.u = ((unsigned int)h) << 16; return c.f;
}
__device__ __forceinline__ bf16_t f2b(float f) {
    union { float f; unsigned int u; } c; c.f = f;
    unsigned int r = c.u + 0x7fffu + ((c.u >> 16) & 1u);
    return (bf16_t)(r >> 16);
}

__device__ __forceinline__ float4 load4(const float* p) { return *(const float4*)p; }
__device__ __forceinline__ float4 load4(const bf16_t* p) {
    ushort4 u = *(const ushort4*)p;
    return make_float4(b2f(u.x), b2f(u.y), b2f(u.z), b2f(u.w));
}

__device__ __forceinline__ float gelu_tanh(float x) {
    float x3 = x * x * x;
    float t  = tanhf(0.7978845608028654f * (x + 0.044715f * x3));
    return 0.5f * x * (1.0f + t);
}
__device__ __forceinline__ float silu(float x) { return x / (1.0f + expf(-x)); }

// ---------------- GEMM: C[M,N](bf16) = A[M,K] @ B[K,N](fp32) ----------------
// EPI: 0 none | 1 bias+gelu | 2 bias | 3 mul-by-existing-C | 4 silu
template <typename TA, int EPI>
__global__ __launch_bounds__(256) void gemm_k(const TA* __restrict__ A,
                                              const float* __restrict__ B,
                                              bf16_t* __restrict__ C,
                                              int M, int N, int K,
                                              const float* __restrict__ bias) {
    __shared__ float sA[16][68];
    __shared__ float sB[16][68];
    const int tid  = threadIdx.x;
    const int bm   = blockIdx.y * 64;
    const int bn   = blockIdx.x * 64;
    const int arow = tid >> 2;            // 0..63
    const int acol = (tid & 3) << 2;      // 0,4,8,12
    const int brow = tid >> 4;            // 0..15
    const int bcol = (tid & 15) << 2;     // 0..60
    const int tx   = tid & 15;
    const int ty   = tid >> 4;

    float acc[4][4] = {};

    for (int k0 = 0; k0 < K; k0 += 16) {
        float4 av = load4(&A[(size_t)(bm + arow) * K + k0 + acol]);
        float4 bv = *(const float4*)&B[(size_t)(k0 + brow) * N + bn + bcol];
        __syncthreads();
        sA[acol + 0][arow] = av.x;
        sA[acol + 1][arow] = av.y;
        sA[acol + 2][arow] = av.z;
        sA[acol + 3][arow] = av.w;
        *(float4*)&sB[brow][bcol] = bv;
        __syncthreads();
#pragma unroll
        for (int kk = 0; kk < 16; ++kk) {
            float a0 = sA[kk][ty * 4 + 0];
            float a1 = sA[kk][ty * 4 + 1];
            float a2 = sA[kk][ty * 4 + 2];
            float a3 = sA[kk][ty * 4 + 3];
            float b0 = sB[kk][tx * 4 + 0];
            float b1 = sB[kk][tx * 4 + 1];
            float b2 = sB[kk][tx * 4 + 2];
            float b3 = sB[kk][tx * 4 + 3];
            acc[0][0] += a0 * b0; acc[0][1] += a0 * b1; acc[0][2] += a0 * b2; acc[0][3] += a0 * b3;
            acc[1][0] += a1 * b0; acc[1][1] += a1 * b1; acc[1][2] += a1 * b2; acc[1][3] += a1 * b3;
            acc[2][0] += a2 * b0; acc[2][1] += a2 * b1; acc[2][2] += a2 * b2; acc[2][3] += a2 * b3;
            acc[3][0] += a3 * b0; acc[3][1] += a3 * b1; acc[3][2] += a3 * b2; acc[3][3] += a3 * b3;
        }
    }

#pragma unroll
    for (int i = 0; i < 4; ++i) {
        size_t row = (size_t)(bm + ty * 4 + i);
        int    col = bn + tx * 4;
        bf16_t* cp = &C[row * N + col];
        float o0 = acc[i][0], o1 = acc[i][1], o2 = acc[i][2], o3 = acc[i][3];
        if (EPI == 1 || EPI == 2) {
            o0 += bias[col + 0]; o1 += bias[col + 1];
            o2 += bias[col + 2]; o3 += bias[col + 3];
        }
        if (EPI == 1) { o0 = gelu_tanh(o0); o1 = gelu_tanh(o1); o2 = gelu_tanh(o2); o3 = gelu_tanh(o3); }
        if (EPI == 4) { o0 = silu(o0); o1 = silu(o1); o2 = silu(o2); o3 = silu(o3); }
        if (EPI == 3) {
            ushort4 e = *(const ushort4*)cp;
            o0 *= b2f(e.x); o1 *= b2f(e.y); o2 *= b2f(e.z); o3 *= b2f(e.w);
        }
        ushort4 st;
        st.x = f2b(o0); st.y = f2b(o1); st.z = f2b(o2); st.w = f2b(o3);
        *(ushort4*)cp = st;
    }
}

// ---------------- a transform: a_c = sigmoid(|a|) * a/|a| (bf16 in place) ----
__global__ __launch_bounds__(256) void a_transform_k(bf16_t* __restrict__ a2d) {
    int gid = blockIdx.x * 256 + threadIdx.x;   // < M*D
    int j   = gid & 1023;
    int row = gid >> 10;
    size_t i0 = (size_t)row * 2048 + j;
    float ar = b2f(a2d[i0]), ai = b2f(a2d[i0 + 1024]);
    float mag = sqrtf(ar * ar + ai * ai);
    float sg  = 1.0f / (1.0f + expf(-mag));
    float re, im;
    if (mag > 1e-30f) { float s = sg / mag; re = ar * s; im = ai * s; }
    else              { re = sg; im = 0.0f; }
    a2d[i0]        = f2b(re);
    a2d[i0 + 1024] = f2b(im);
}

// ---------------- chunked complex scan --------------------------------------
// task id = (c*B + b)*D + d  -> consecutive d within a wave (coalesced)
__global__ __launch_bounds__(256) void scan_pass1_k(const bf16_t* __restrict__ a2d,
                                                    const bf16_t* __restrict__ kv,
                                                    float4* __restrict__ chunk) {
    int tid = blockIdx.x * 256 + threadIdx.x;    // < CBD
    int d   = tid & 1023;
    int t1  = tid >> 10;
    int b   = t1 & 3;
    int c   = t1 >> 2;
    int t0  = c * CLEN;
    int rbase = b * Ss;
    float Are = 1.0f, Aim = 0.0f, Hre = 0.0f, Him = 0.0f;
    for (int t = t0; t < t0 + CLEN; ++t) {
        int r = rbase + t;
        float are = b2f(a2d[(size_t)r * 2048 + d]);
        float aim = b2f(a2d[(size_t)r * 2048 + 1024 + d]);
        float kvv = b2f(kv[(size_t)r * 1024 + d]);
        float hre = are * Hre - aim * Him + kvv;
        float him = are * Him + aim * Hre;
        Hre = hre; Him = him;
        float pre = are * Are - aim * Aim;
        float pim = are * Aim + aim * Are;
        Are = pre; Aim = pim;
    }
    chunk[tid] = make_float4(Are, Aim, Hre, Him);
}

__global__ __launch_bounds__(256) void scan_pass2_k(const float4* __restrict__ chunk,
                                                    float2* __restrict__ carry,
                                                    float* __restrict__ stats) {
    int tid = blockIdx.x * blockDim.x + threadIdx.x;  // < B*D = 4096
    if (tid < 512) stats[tid] = 0.0f;                 // ws is poisoned: zero gn stats
    float hre = 0.0f, him = 0.0f;
    for (int c = 0; c < CHUNKS; ++c) {
        int task = c * BD + tid;
        float4 ch = chunk[task];
        carry[task] = make_float2(hre, him);
        float nre = ch.x * hre - ch.y * him + ch.z;
        float nim = ch.x * him + ch.y * hre + ch.w;
        hre = nre; him = nim;
    }
}

__global__ __launch_bounds__(256) void scan_pass3_k(const bf16_t* __restrict__ a2d,
                                                    const bf16_t* __restrict__ kv,
                                                    const bf16_t* __restrict__ qb,
                                                    const float2* __restrict__ carry,
                                                    bf16_t* __restrict__ yre,
                                                    float* __restrict__ stats) {
    int tid = blockIdx.x * 256 + threadIdx.x;    // < CBD
    int d   = tid & 1023;
    int t1  = tid >> 10;
    int b   = t1 & 3;
    int c   = t1 >> 2;
    int t0  = c * CLEN;
    int rbase = b * Ss;
    float2 cr = carry[tid];
    float hre = cr.x, him = cr.y;
    float sre = 0.0f, sim = 0.0f, s2 = 0.0f;
    for (int t = t0; t < t0 + CLEN; ++t) {
        int r = rbase + t;
        float are = b2f(a2d[(size_t)r * 2048 + d]);
        float aim = b2f(a2d[(size_t)r * 2048 + 1024 + d]);
        float kvv = b2f(kv[(size_t)r * 1024 + d]);
        float nre = are * hre - aim * him + kvv;
        float nim = are * him + aim * hre;
        hre = nre; him = nim;
        float qv  = b2f(qb[(size_t)r * 1024 + d]);
        float yr_ = qv * hre;
        float yi_ = qv * him;
        yre[(size_t)r * 1024 + d] = f2b(yr_);
        sre += yr_; sim += yi_; s2 += yr_ * yr_ + yi_ * yi_;
    }
    // 32 consecutive lanes share one (b, d/32) bucket (d base is 256-aligned)
#pragma unroll
    for (int off = 16; off > 0; off >>= 1) {
        sre += __shfl_down(sre, off, 32);
        sim += __shfl_down(sim, off, 32);
        s2  += __shfl_down(s2,  off, 32);
    }
    if ((threadIdx.x & 31) == 0) {
        int idx = (b * 32 + (d >> 5)) * 4;
        atomicAdd(&stats[idx + 0], sre);
        atomicAdd(&stats[idx + 1], sim);
        atomicAdd(&stats[idx + 2], s2);
    }
}

// ---------------- groupnorm (real part) + silu-gate, bf16 in place ----------
__global__ __launch_bounds__(256) void gn_gate_k(bf16_t* __restrict__ y,
                                                 const bf16_t* __restrict__ g,
                                                 const float* __restrict__ stats,
                                                 const float* __restrict__ gn_scale,
                                                 const float* __restrict__ gn_bias) {
    size_t gid = (size_t)blockIdx.x * 256 + threadIdx.x;  // < M*D
    int d   = (int)(gid & 1023);
    int row = (int)(gid >> 10);                // b*S + s
    int b   = row >> 12;
    int grp = d >> 5;
    const float* st = &stats[(b * 32 + grp) * 4];
    const float invN = 1.0f / 131072.0f;       // S * 32
    float mre = st[0] * invN;
    float mim = st[1] * invN;
    float var = st[2] * invN - mre * mre - mim * mim;
    float rstd = rsqrtf(var + EPSN);
    float re = (b2f(y[gid]) - mre) * rstd * gn_scale[d] + gn_bias[d];
    y[gid] = f2b(re * b2f(g[gid]));            // g already silu'd (real)
}

// ---------------- layernorm over D=1024: out = LN(a + b) --------------------
__device__ __forceinline__ float ldf(const float* p, size_t i)  { return p[i]; }
__device__ __forceinline__ float ldf(const bf16_t* p, size_t i) { return b2f(p[i]); }
__device__ __forceinline__ void  stf(float* p, size_t i, float v)  { p[i] = v; }
__device__ __forceinline__ void  stf(bf16_t* p, size_t i, float v) { p[i] = f2b(v); }

__device__ __forceinline__ float block_reduce_sum(float v, float* s4, int tid) {
#pragma unroll
    for (int off = 32; off > 0; off >>= 1) v += __shfl_down(v, off, 64);
    __syncthreads();
    if ((tid & 63) == 0) s4[tid >> 6] = v;
    __syncthreads();
    return s4[0] + s4[1] + s4[2] + s4[3];
}

template <typename TA, typename TB, typename TO>
__global__ __launch_bounds__(256) void ln_k(const TA* __restrict__ a,
                                            const TB* __restrict__ b,
                                            const float* __restrict__ scale,
                                            const float* __restrict__ bias,
                                            TO* __restrict__ out) {
    __shared__ float s4[4];
    int row = blockIdx.x;
    size_t base = (size_t)row * 1024;
    int tid = threadIdx.x;
    float v[4];
    float s = 0.0f;
#pragma unroll
    for (int i = 0; i < 4; ++i) {
        int d = tid + i * 256;
        v[i] = ldf(a, base + d) + ldf(b, base + d);
        s += v[i];
    }
    float mu = block_reduce_sum(s, s4, tid) * (1.0f / 1024.0f);
    float s2 = 0.0f;
#pragma unroll
    for (int i = 0; i < 4; ++i) {
        float dv = v[i] - mu;
        s2 += dv * dv;
    }
    float var = block_reduce_sum(s2, s4, tid) * (1.0f / 1024.0f);
    float rstd = rsqrtf(var + EPSN);
#pragma unroll
    for (int i = 0; i < 4; ++i) {
        int d = tid + i * 256;
        stf(out, base + d, (v[i] - mu) * rstd * scale[d] + bias[d]);
    }
}

// ---------------------------------------------------------------------------
extern "C" void kernel_launch(void* const* d_in, const int* in_sizes, int n_in,
                              void* d_out, int out_size, void* d_ws, size_t ws_size,
                              hipStream_t stream) {
    const float* x        = (const float*)d_in[0];
    const float* Wq       = (const float*)d_in[1];
    const float* Wk       = (const float*)d_in[2];
    const float* Wv       = (const float*)d_in[3];
    const float* Wa       = (const float*)d_in[4];
    const float* Wg       = (const float*)d_in[5];
    const float* Wo       = (const float*)d_in[6];
    const float* gn_scale = (const float*)d_in[7];
    const float* gn_bias  = (const float*)d_in[8];
    const float* ln1_s    = (const float*)d_in[9];
    const float* ln1_b    = (const float*)d_in[10];
    const float* W1       = (const float*)d_in[11];
    const float* b1       = (const float*)d_in[12];
    const float* W2       = (const float*)d_in[13];
    const float* b2       = (const float*)d_in[14];
    const float* ln2_s    = (const float*)d_in[15];
    const float* ln2_b    = (const float*)d_in[16];
    float* out = (float*)d_out;

    char* base = (char*)d_ws;
    bf16_t* qb  = (bf16_t*)(base);
    bf16_t* kvb = (bf16_t*)(base + MDb);
    bf16_t* ab  = (bf16_t*)(base + 2 * MDb);          // [M, 2D]
    bf16_t* gb  = (bf16_t*)(base + 4 * MDb);
    bf16_t* yb  = (bf16_t*)(base + 5 * MDb);
    float4* chunk = (float4*)(base + 6 * MDb);
    float2* carry = (float2*)(base + 6 * MDb + (size_t)CBD * 16);
    float*  stats = (float*)(base + 6 * MDb + (size_t)CBD * 16 + (size_t)CBD * 8);
    // aliases (lifetimes verified):
    bf16_t* yo = qb;     // Wo output; q dead after pass3
    bf16_t* x1 = kvb;    // post-ln1; kv dead after pass3
    bf16_t* h1 = ab;     // [M,F] bf16 = 4*MDb spans ab+gb+yb, all dead by MLP
    bf16_t* h2 = qb;     // W2 output; yo dead after ln1

    dim3 blk(256);

    // 1. input projections (v fused with k -> kv ; g fused with silu)
    gemm_k<float, 0><<<dim3(Dd / 64, Mrows / 64), blk, 0, stream>>>(x, Wq, qb, Mrows, Dd, Dd, nullptr);
    gemm_k<float, 0><<<dim3(Dd / 64, Mrows / 64), blk, 0, stream>>>(x, Wk, kvb, Mrows, Dd, Dd, nullptr);
    gemm_k<float, 3><<<dim3(Dd / 64, Mrows / 64), blk, 0, stream>>>(x, Wv, kvb, Mrows, Dd, Dd, nullptr);
    gemm_k<float, 0><<<dim3(2 * Dd / 64, Mrows / 64), blk, 0, stream>>>(x, Wa, ab, Mrows, 2 * Dd, Dd, nullptr);
    gemm_k<float, 4><<<dim3(Dd / 64, Mrows / 64), blk, 0, stream>>>(x, Wg, gb, Mrows, Dd, Dd, nullptr);

    // 2. a transform
    a_transform_k<<<MD / 256, blk, 0, stream>>>(ab);

    // 3. chunked scan
    scan_pass1_k<<<CBD / 256, blk, 0, stream>>>(ab, kvb, chunk);
    scan_pass2_k<<<BD / 256, blk, 0, stream>>>(chunk, carry, stats);
    scan_pass3_k<<<CBD / 256, blk, 0, stream>>>(ab, kvb, qb, carry, yb, stats);

    // 4. groupnorm + gate (in place on yb)
    gn_gate_k<<<MD / 256, blk, 0, stream>>>(yb, gb, stats, gn_scale, gn_bias);

    // 5. output projection + ln1
    gemm_k<bf16_t, 0><<<dim3(Dd / 64, Mrows / 64), blk, 0, stream>>>(yb, Wo, yo, Mrows, Dd, Dd, nullptr);
    ln_k<float, bf16_t, bf16_t><<<Mrows, blk, 0, stream>>>(x, yo, ln1_s, ln1_b, x1);

    // 6. MLP
    gemm_k<bf16_t, 1><<<dim3(Ff / 64, Mrows / 64), blk, 0, stream>>>(x1, W1, h1, Mrows, Ff, Dd, b1);
    gemm_k<bf16_t, 2><<<dim3(Dd / 64, Mrows / 64), blk, 0, stream>>>(h1, W2, h2, Mrows, Dd, Ff, b2);

    // 7. final layernorm -> out
    ln_k<bf16_t, bf16_t, float><<<Mrows, blk, 0, stream>>>(x1, h2, ln2_s, ln2_b, out);
}

// Round 4
// 1953.675 us; speedup vs baseline: 3.7463x; 3.7463x over previous
//
#include <hip/hip_runtime.h>
#include <cstdint>
#include <cstddef>

// ---------------------------------------------------------------------------
// GateLoop block, round 3: bf16 MFMA GEMMs with SPLIT-BF16 WEIGHTS (2-pass):
// W = W_hi + W_lo, B operand laid out [N, 2K] (hi|lo), GEMM loops Kt=2K with
// A column index k0 & (K-1). Restores ~fp32 weight precision at 2x MFMA cost
// (round 3 failed 0.117 vs 0.101 from single-bf16 weights; round 2 passed
// 0.031 with fp32 weights). Transformed gate `a` stored fp16 (|a|<=1, 10
// mantissa bits) to reduce the error-amplified scan path.
//
// ws layout (MiB):
//   0 W12 | 16 W22 | 32 Wq2 | 36 Wk2 | 40 Wv2 | 44 Wg2 | 48 Wo2 | 52 Wa2 |
//   60 chunk | 64 carry | 66 stats | 67 xb(->yb) | 99 kvb | 131 qb(->yo) |
//   163 gb(->x1) | 195 end.
//   h1 [M,F] bf16 = 128 MiB overlays 32..160 (proj weights, scratch, yb, kvb,
//   part of yo -- all dead by W1 GEMM).  a[M,2D] + h2[M,D]fp32 live in d_out.
// ---------------------------------------------------------------------------

#define EPSN 1e-6f

typedef unsigned short bf16_t;
typedef unsigned short fp16_t;
typedef __bf16 bf16x8 __attribute__((ext_vector_type(8)));
typedef float  f32x4  __attribute__((ext_vector_type(4)));

static constexpr int    Bb     = 4;
static constexpr int    Ss     = 4096;
static constexpr int    Dd     = 1024;
static constexpr int    Ff     = 4096;
static constexpr int    Mrows  = Bb * Ss;                  // 16384
static constexpr size_t MD     = (size_t)Mrows * Dd;       // 16777216
static constexpr int    CHUNKS = 64;
static constexpr int    CLEN   = Ss / CHUNKS;              // 64
static constexpr int    BD     = Bb * Dd;                  // 4096
static constexpr int    CBD    = CHUNKS * BD;              // 262144
static constexpr size_t MiB    = 1024 * 1024;

__device__ __forceinline__ float b2f(bf16_t h) {
    union { unsigned int u; float f; } c; c.u = ((unsigned int)h) << 16; return c.f;
}
__device__ __forceinline__ bf16_t f2b(float f) {
    union { float f; unsigned int u; } c; c.f = f;
    unsigned int r = c.u + 0x7fffu + ((c.u >> 16) & 1u);
    return (bf16_t)(r >> 16);
}
__device__ __forceinline__ fp16_t f2h(float f) {
    union { _Float16 h; unsigned short u; } c; c.h = (_Float16)f; return c.u;
}
__device__ __forceinline__ float h2f(fp16_t u) {
    union { unsigned short u; _Float16 h; } c; c.u = u; return (float)c.h;
}

__device__ __forceinline__ float gelu_tanh(float x) {
    float x3 = x * x * x;
    float t  = tanhf(0.7978845608028654f * (x + 0.044715f * x3));
    return 0.5f * x * (1.0f + t);
}
__device__ __forceinline__ float silu(float x) { return x / (1.0f + expf(-x)); }

// async global->LDS, 16 B per lane; lds dest = base + lane*16 (wave-uniform base)
__device__ __forceinline__ void async16(const void* g, void* l) {
    __builtin_amdgcn_global_load_lds(
        (const __attribute__((address_space(1))) unsigned int*)(uintptr_t)g,
        (__attribute__((address_space(3))) unsigned int*)(uintptr_t)l,
        16, 0, 0);
}

// ---------------- MFMA GEMM: C[M,N] = A[M,Ka] @ B2[N,Kt]^T ------------------
// Loops k0 over Kt; A column = k0 & (Ka-1). For split weights Kt=2*Ka (hi|lo);
// a plain GEMM is Kt==Ka. EPI: 0 none | 1 bias+gelu | 2 bias | 3 mul-C | 4 silu
template <int EPI, typename TC>
__global__ __launch_bounds__(256) void mgemm_k(const bf16_t* __restrict__ A,
                                               const bf16_t* __restrict__ Bt,
                                               TC* __restrict__ C,
                                               int M, int N, int Kt, int Ka,
                                               const float* __restrict__ bias) {
    __shared__ short As[128 * 32];   // [row][k] row-major, 32 bf16/row
    __shared__ short Bs[128 * 32];   // [col][k] row-major
    const int tid  = threadIdx.x;
    const int wave = tid >> 6;
    const int lane = tid & 63;
    const int bm   = blockIdx.y * 128;
    const int bn   = blockIdx.x * 128;
    const int rw   = (wave & 1) * 64;
    const int cw   = (wave >> 1) * 64;
    const int kmask = Ka - 1;        // Ka is a power of two

    const bf16_t* gA = A  + (size_t)(bm + wave * 32 + (lane >> 2)) * Ka + (lane & 3) * 8;
    const bf16_t* gB = Bt + (size_t)(bn + wave * 32 + (lane >> 2)) * Kt + (lane & 3) * 8;
    short* lA = As + wave * 1024;
    short* lB = Bs + wave * 1024;

    f32x4 acc[4][4] = {};

    const int fr = lane & 15;
    const int fk = (lane >> 4) * 8;

    for (int k0 = 0; k0 < Kt; k0 += 32) {
        const int ka = k0 & kmask;
        __syncthreads();
        async16(gA + ka,           lA);
        async16(gA + 16 * Ka + ka, lA + 512);
        async16(gB + k0,           lB);
        async16(gB + 16 * Kt + k0, lB + 512);
        __syncthreads();
        bf16x8 af[4], bfr[4];
#pragma unroll
        for (int i = 0; i < 4; ++i)
            af[i] = *(const bf16x8*)&As[(rw + i * 16 + fr) * 32 + fk];
#pragma unroll
        for (int j = 0; j < 4; ++j)
            bfr[j] = *(const bf16x8*)&Bs[(cw + j * 16 + fr) * 32 + fk];
#pragma unroll
        for (int i = 0; i < 4; ++i)
#pragma unroll
            for (int j = 0; j < 4; ++j)
                acc[i][j] = __builtin_amdgcn_mfma_f32_16x16x32_bf16(af[i], bfr[j], acc[i][j], 0, 0, 0);
    }

    const int er = (lane >> 4) * 4;
    const int ec = lane & 15;
#pragma unroll
    for (int i = 0; i < 4; ++i) {
#pragma unroll
        for (int j = 0; j < 4; ++j) {
            const int col = bn + cw + j * 16 + ec;
#pragma unroll
            for (int r = 0; r < 4; ++r) {
                const size_t row = (size_t)(bm + rw + i * 16 + er + r);
                float o = acc[i][j][r];
                if (EPI == 1 || EPI == 2) o += bias[col];
                if (EPI == 1) o = gelu_tanh(o);
                if (EPI == 4) o = silu(o);
                if (EPI == 3) o *= b2f(((const bf16_t*)C)[row * N + col]);
                if (sizeof(TC) == 4) ((float*)C)[row * N + col] = o;
                else                 ((bf16_t*)C)[row * N + col] = f2b(o);
            }
        }
    }
}

// ------- weight transpose+convert+split: W[K,N] -> Wt[N,2K] (hi|lo) ---------
__global__ __launch_bounds__(256) void wtrans2_k(const float* __restrict__ W,
                                                 bf16_t* __restrict__ Wt,
                                                 int K, int N) {
    __shared__ float t[32][33];
    const int n0 = blockIdx.x * 32, k0 = blockIdx.y * 32;
    const int tx = threadIdx.x & 31, ty = threadIdx.x >> 5;   // 8 rows
#pragma unroll
    for (int i = 0; i < 32; i += 8)
        t[ty + i][tx] = W[(size_t)(k0 + ty + i) * N + n0 + tx];
    __syncthreads();
#pragma unroll
    for (int i = 0; i < 32; i += 8) {
        float w = t[tx][ty + i];
        bf16_t hi = f2b(w);
        float lo  = w - b2f(hi);
        size_t base = (size_t)(n0 + ty + i) * (2 * K) + k0 + tx;
        Wt[base]     = hi;
        Wt[base + K] = f2b(lo);
    }
}

// ---------------- x fp32 -> bf16 --------------------------------------------
__global__ __launch_bounds__(256) void f2b_k(const float* __restrict__ x,
                                             bf16_t* __restrict__ xb) {
    size_t i = ((size_t)blockIdx.x * 256 + threadIdx.x) * 4;
    float4 v = *(const float4*)&x[i];
    ushort4 s;
    s.x = f2b(v.x); s.y = f2b(v.y); s.z = f2b(v.z); s.w = f2b(v.w);
    *(ushort4*)&xb[i] = s;
}

// ------- a transform: a_c = sigmoid(|a|)*a/|a|; bf16 in -> fp16 out ---------
__global__ __launch_bounds__(256) void a_transform_k(unsigned short* __restrict__ a2d) {
    int gid = blockIdx.x * 256 + threadIdx.x;   // < M*D
    int j   = gid & 1023;
    int row = gid >> 10;
    size_t i0 = (size_t)row * 2048 + j;
    float ar = b2f(a2d[i0]), ai = b2f(a2d[i0 + 1024]);
    float mag = sqrtf(ar * ar + ai * ai);
    float sg  = 1.0f / (1.0f + expf(-mag));
    float re, im;
    if (mag > 1e-30f) { float s = sg / mag; re = ar * s; im = ai * s; }
    else              { re = sg; im = 0.0f; }
    a2d[i0]        = f2h(re);
    a2d[i0 + 1024] = f2h(im);
}

// ---------------- chunked complex scan (a is fp16) --------------------------
__global__ __launch_bounds__(256) void scan_pass1_k(const fp16_t* __restrict__ a2d,
                                                    const bf16_t* __restrict__ kv,
                                                    float4* __restrict__ chunk) {
    int tid = blockIdx.x * 256 + threadIdx.x;    // < CBD
    int d   = tid & 1023;
    int t1  = tid >> 10;
    int b   = t1 & 3;
    int c   = t1 >> 2;
    int t0  = c * CLEN;
    int rbase = b * Ss;
    float Are = 1.0f, Aim = 0.0f, Hre = 0.0f, Him = 0.0f;
    for (int t = t0; t < t0 + CLEN; ++t) {
        int r = rbase + t;
        float are = h2f(a2d[(size_t)r * 2048 + d]);
        float aim = h2f(a2d[(size_t)r * 2048 + 1024 + d]);
        float kvv = b2f(kv[(size_t)r * 1024 + d]);
        float hre = are * Hre - aim * Him + kvv;
        float him = are * Him + aim * Hre;
        Hre = hre; Him = him;
        float pre = are * Are - aim * Aim;
        float pim = are * Aim + aim * Are;
        Are = pre; Aim = pim;
    }
    chunk[tid] = make_float4(Are, Aim, Hre, Him);
}

__global__ __launch_bounds__(256) void scan_pass2_k(const float4* __restrict__ chunk,
                                                    float2* __restrict__ carry,
                                                    float* __restrict__ stats) {
    int tid = blockIdx.x * blockDim.x + threadIdx.x;  // < B*D = 4096
    if (tid < 512) stats[tid] = 0.0f;                 // ws is poisoned: zero gn stats
    float hre = 0.0f, him = 0.0f;
    for (int c = 0; c < CHUNKS; ++c) {
        int task = c * BD + tid;
        float4 ch = chunk[task];
        carry[task] = make_float2(hre, him);
        float nre = ch.x * hre - ch.y * him + ch.z;
        float nim = ch.x * him + ch.y * hre + ch.w;
        hre = nre; him = nim;
    }
}

__global__ __launch_bounds__(256) void scan_pass3_k(const fp16_t* __restrict__ a2d,
                                                    const bf16_t* __restrict__ kv,
                                                    const bf16_t* __restrict__ qb,
                                                    const float2* __restrict__ carry,
                                                    bf16_t* __restrict__ yre,
                                                    float* __restrict__ stats) {
    int tid = blockIdx.x * 256 + threadIdx.x;    // < CBD
    int d   = tid & 1023;
    int t1  = tid >> 10;
    int b   = t1 & 3;
    int c   = t1 >> 2;
    int t0  = c * CLEN;
    int rbase = b * Ss;
    float2 cr = carry[tid];
    float hre = cr.x, him = cr.y;
    float sre = 0.0f, sim = 0.0f, s2 = 0.0f;
    for (int t = t0; t < t0 + CLEN; ++t) {
        int r = rbase + t;
        float are = h2f(a2d[(size_t)r * 2048 + d]);
        float aim = h2f(a2d[(size_t)r * 2048 + 1024 + d]);
        float kvv = b2f(kv[(size_t)r * 1024 + d]);
        float nre = are * hre - aim * him + kvv;
        float nim = are * him + aim * hre;
        hre = nre; him = nim;
        float qv  = b2f(qb[(size_t)r * 1024 + d]);
        float yr_ = qv * hre;
        float yi_ = qv * him;
        yre[(size_t)r * 1024 + d] = f2b(yr_);
        sre += yr_; sim += yi_; s2 += yr_ * yr_ + yi_ * yi_;
    }
#pragma unroll
    for (int off = 16; off > 0; off >>= 1) {
        sre += __shfl_down(sre, off, 32);
        sim += __shfl_down(sim, off, 32);
        s2  += __shfl_down(s2,  off, 32);
    }
    if ((threadIdx.x & 31) == 0) {
        int idx = (b * 32 + (d >> 5)) * 4;
        atomicAdd(&stats[idx + 0], sre);
        atomicAdd(&stats[idx + 1], sim);
        atomicAdd(&stats[idx + 2], s2);
    }
}

// ---------------- groupnorm (real part) + silu-gate, bf16 in place ----------
__global__ __launch_bounds__(256) void gn_gate_k(bf16_t* __restrict__ y,
                                                 const bf16_t* __restrict__ g,
                                                 const float* __restrict__ stats,
                                                 const float* __restrict__ gn_scale,
                                                 const float* __restrict__ gn_bias) {
    size_t gid = (size_t)blockIdx.x * 256 + threadIdx.x;  // < M*D
    int d   = (int)(gid & 1023);
    int row = (int)(gid >> 10);
    int b   = row >> 12;
    int grp = d >> 5;
    const float* st = &stats[(b * 32 + grp) * 4];
    const float invN = 1.0f / 131072.0f;       // S * (D/G)
    float mre = st[0] * invN;
    float mim = st[1] * invN;
    float var = st[2] * invN - mre * mre - mim * mim;
    float rstd = rsqrtf(var + EPSN);
    float re = (b2f(y[gid]) - mre) * rstd * gn_scale[d] + gn_bias[d];
    y[gid] = f2b(re * b2f(g[gid]));
}

// ---------------- layernorm over D=1024: out = LN(a + b) --------------------
__device__ __forceinline__ float ldf(const float* p, size_t i)  { return p[i]; }
__device__ __forceinline__ float ldf(const bf16_t* p, size_t i) { return b2f(p[i]); }
__device__ __forceinline__ void  stf(float* p, size_t i, float v)  { p[i] = v; }
__device__ __forceinline__ void  stf(bf16_t* p, size_t i, float v) { p[i] = f2b(v); }

__device__ __forceinline__ float block_reduce_sum(float v, float* s4, int tid) {
#pragma unroll
    for (int off = 32; off > 0; off >>= 1) v += __shfl_down(v, off, 64);
    __syncthreads();
    if ((tid & 63) == 0) s4[tid >> 6] = v;
    __syncthreads();
    return s4[0] + s4[1] + s4[2] + s4[3];
}

template <typename TA, typename TB, typename TO>
__global__ __launch_bounds__(256) void ln_k(const TA* __restrict__ a,
                                            const TB* __restrict__ b,
                                            const float* __restrict__ scale,
                                            const float* __restrict__ bias,
                                            TO* __restrict__ out) {
    __shared__ float s4[4];
    int row = blockIdx.x;
    size_t base = (size_t)row * 1024;
    int tid = threadIdx.x;
    float v[4];
    float s = 0.0f;
#pragma unroll
    for (int i = 0; i < 4; ++i) {
        int d = tid + i * 256;
        v[i] = ldf(a, base + d) + ldf(b, base + d);
        s += v[i];
    }
    float mu = block_reduce_sum(s, s4, tid) * (1.0f / 1024.0f);
    float s2 = 0.0f;
#pragma unroll
    for (int i = 0; i < 4; ++i) {
        float dv = v[i] - mu;
        s2 += dv * dv;
    }
    float var = block_reduce_sum(s2, s4, tid) * (1.0f / 1024.0f);
    float rstd = rsqrtf(var + EPSN);
#pragma unroll
    for (int i = 0; i < 4; ++i) {
        int d = tid + i * 256;
        stf(out, base + d, (v[i] - mu) * rstd * scale[d] + bias[d]);
    }
}

// ---------------------------------------------------------------------------
extern "C" void kernel_launch(void* const* d_in, const int* in_sizes, int n_in,
                              void* d_out, int out_size, void* d_ws, size_t ws_size,
                              hipStream_t stream) {
    const float* x        = (const float*)d_in[0];
    const float* Wq       = (const float*)d_in[1];
    const float* Wk       = (const float*)d_in[2];
    const float* Wv       = (const float*)d_in[3];
    const float* Wa       = (const float*)d_in[4];
    const float* Wg       = (const float*)d_in[5];
    const float* Wo       = (const float*)d_in[6];
    const float* gn_scale = (const float*)d_in[7];
    const float* gn_bias  = (const float*)d_in[8];
    const float* ln1_s    = (const float*)d_in[9];
    const float* ln1_b    = (const float*)d_in[10];
    const float* W1       = (const float*)d_in[11];
    const float* b1       = (const float*)d_in[12];
    const float* W2       = (const float*)d_in[13];
    const float* b2       = (const float*)d_in[14];
    const float* ln2_s    = (const float*)d_in[15];
    const float* ln2_b    = (const float*)d_in[16];
    float* out = (float*)d_out;

    char* base = (char*)d_ws;
    bf16_t* W12 = (bf16_t*)(base + 0 * MiB);    // [4096, 2048]
    bf16_t* W22 = (bf16_t*)(base + 16 * MiB);   // [1024, 8192]
    bf16_t* Wq2 = (bf16_t*)(base + 32 * MiB);   // [1024, 2048]
    bf16_t* Wk2 = (bf16_t*)(base + 36 * MiB);
    bf16_t* Wv2 = (bf16_t*)(base + 40 * MiB);
    bf16_t* Wg2 = (bf16_t*)(base + 44 * MiB);
    bf16_t* Wo2 = (bf16_t*)(base + 48 * MiB);
    bf16_t* Wa2 = (bf16_t*)(base + 52 * MiB);   // [2048, 2048]
    float4* chunk = (float4*)(base + 60 * MiB);
    float2* carry = (float2*)(base + 64 * MiB);
    float*  stats = (float*)(base + 66 * MiB);
    bf16_t* xb  = (bf16_t*)(base + 67 * MiB);
    bf16_t* kvb = (bf16_t*)(base + 99 * MiB);
    bf16_t* qb  = (bf16_t*)(base + 131 * MiB);
    bf16_t* gb  = (bf16_t*)(base + 163 * MiB);  // ends 195 MiB
    // aliases (lifetimes verified):
    bf16_t* ab = (bf16_t*)d_out;                // [M,2D] raw a; fp16 after transform
    bf16_t* yb = xb;                            // pass3 out; xb dead after projections
    bf16_t* yo = qb;                            // Wo out; q dead after pass3
    bf16_t* x1 = gb;                            // post-ln1; g dead after gn_gate
    bf16_t* h1 = (bf16_t*)(base + 32 * MiB);    // [M,F] 128 MiB, 32..160 all dead
    float*  h2 = (float*)d_out;                 // fp32 [M,D]; a dead after pass3

    dim3 blk(256);

    // 0. conversions: x -> bf16; weights -> transposed split bf16 [N,2K]
    f2b_k<<<Mrows, blk, 0, stream>>>(x, xb);
    wtrans2_k<<<dim3(32, 32),  blk, 0, stream>>>(Wq, Wq2, Dd, Dd);
    wtrans2_k<<<dim3(32, 32),  blk, 0, stream>>>(Wk, Wk2, Dd, Dd);
    wtrans2_k<<<dim3(32, 32),  blk, 0, stream>>>(Wv, Wv2, Dd, Dd);
    wtrans2_k<<<dim3(32, 32),  blk, 0, stream>>>(Wg, Wg2, Dd, Dd);
    wtrans2_k<<<dim3(32, 32),  blk, 0, stream>>>(Wo, Wo2, Dd, Dd);
    wtrans2_k<<<dim3(64, 32),  blk, 0, stream>>>(Wa, Wa2, Dd, 2 * Dd);
    wtrans2_k<<<dim3(128, 32), blk, 0, stream>>>(W1, W12, Dd, Ff);
    wtrans2_k<<<dim3(32, 128), blk, 0, stream>>>(W2, W22, Ff, Dd);

    // 1. input projections (Kt = 2K split)
    mgemm_k<0, bf16_t><<<dim3(Dd / 128, Mrows / 128), blk, 0, stream>>>(xb, Wq2, qb, Mrows, Dd, 2 * Dd, Dd, nullptr);
    mgemm_k<0, bf16_t><<<dim3(Dd / 128, Mrows / 128), blk, 0, stream>>>(xb, Wk2, kvb, Mrows, Dd, 2 * Dd, Dd, nullptr);
    mgemm_k<3, bf16_t><<<dim3(Dd / 128, Mrows / 128), blk, 0, stream>>>(xb, Wv2, kvb, Mrows, Dd, 2 * Dd, Dd, nullptr);
    mgemm_k<0, bf16_t><<<dim3(2 * Dd / 128, Mrows / 128), blk, 0, stream>>>(xb, Wa2, ab, Mrows, 2 * Dd, 2 * Dd, Dd, nullptr);
    mgemm_k<4, bf16_t><<<dim3(Dd / 128, Mrows / 128), blk, 0, stream>>>(xb, Wg2, gb, Mrows, Dd, 2 * Dd, Dd, nullptr);

    // 2. a transform (bf16 -> fp16, in place in d_out)
    a_transform_k<<<MD / 256, blk, 0, stream>>>((unsigned short*)ab);

    // 3. chunked scan
    scan_pass1_k<<<CBD / 256, blk, 0, stream>>>((const fp16_t*)ab, kvb, chunk);
    scan_pass2_k<<<BD / 256, blk, 0, stream>>>(chunk, carry, stats);
    scan_pass3_k<<<CBD / 256, blk, 0, stream>>>((const fp16_t*)ab, kvb, qb, carry, yb, stats);

    // 4. groupnorm + gate (in place on yb)
    gn_gate_k<<<MD / 256, blk, 0, stream>>>(yb, gb, stats, gn_scale, gn_bias);

    // 5. output projection + ln1 (x1 -> gb slot; g dead)
    mgemm_k<0, bf16_t><<<dim3(Dd / 128, Mrows / 128), blk, 0, stream>>>(yb, Wo2, yo, Mrows, Dd, 2 * Dd, Dd, nullptr);
    ln_k<float, bf16_t, bf16_t><<<Mrows, blk, 0, stream>>>(x, yo, ln1_s, ln1_b, x1);

    // 6. MLP (h1 overlays 32..160 MiB; h2 -> d_out fp32)
    mgemm_k<1, bf16_t><<<dim3(Ff / 128, Mrows / 128), blk, 0, stream>>>(x1, W12, h1, Mrows, Ff, 2 * Dd, Dd, b1);
    mgemm_k<2, float ><<<dim3(Dd / 128, Mrows / 128), blk, 0, stream>>>(h1, W22, h2, Mrows, Dd, 2 * Ff, Ff, b2);

    // 7. final layernorm -> out (in place over h2: per-thread read-then-write)
    ln_k<bf16_t, float, float><<<Mrows, blk, 0, stream>>>(x1, h2, ln2_s, ln2_b, out);
}

// Round 5
// 1283.823 us; speedup vs baseline: 5.7009x; 1.5218x over previous
//
#include <hip/hip_runtime.h>
#include <cstdint>
#include <cstddef>

// ---------------------------------------------------------------------------
// GateLoop block, round 5: all-FP16 MFMA GEMMs (single pass, no split).
// Rationale: rounds 2/3/4 showed the bf16 *activation* rounding dominated the
// error (0.088 of 0.0928), not weights. fp16 (10 mantissa bits) kills both
// terms at once and halves GEMM FLOPs+bytes vs round 4's split-bf16.
//
// Pipeline:
//   0. x -> fp16; weights -> transposed fp16 [N,K]
//   1. mgemm x@{Wq,Wk,Wv,Wa,Wg}; v fused *k -> kv; g fused silu (all fp16 out)
//   2. a_transform in place (fp16, lives in d_out)
//   3. chunked scan (3 passes, fp32 state); Im(y) only as GN stats (atomics)
//   4. gn_gate (fp16); 5. mgemm y@Wo -> yo; ln1 -> x1 (fp16)
//   6. mgemm x1@W1(+b1,gelu) -> h1 ; mgemm h1@W2(+b2) -> h2 (fp32, d_out)
//   7. ln2(x1 + h2) -> out (in place over h2, per-thread read-then-write)
//
// ws layout (MiB): 0 W1T(8) | 8 W2T(8) | 16 WqT | 18 WkT | 20 WvT | 22 WgT |
//   24 WoT | 26 WaT(4) | 30 chunk(4) | 34 carry(2) | 36 stats | 37 xb(32) |
//   69 kvb | 101 qb | 133 gb | 165 yb | 197 end.  (197 MiB proven safe r2)
// Aliases: yo->qb, x1->xb, h1(128 MiB)->69..197, a & h2 -> d_out.
// ---------------------------------------------------------------------------

#define EPSN 1e-6f

typedef _Float16 f16;
typedef _Float16 f16x8 __attribute__((ext_vector_type(8)));
typedef _Float16 f16x4 __attribute__((ext_vector_type(4)));
typedef float    f32x4 __attribute__((ext_vector_type(4)));

static constexpr int    Bb     = 4;
static constexpr int    Ss     = 4096;
static constexpr int    Dd     = 1024;
static constexpr int    Ff     = 4096;
static constexpr int    Mrows  = Bb * Ss;                  // 16384
static constexpr size_t MD     = (size_t)Mrows * Dd;       // 16777216
static constexpr int    CHUNKS = 64;
static constexpr int    CLEN   = Ss / CHUNKS;              // 64
static constexpr int    BD     = Bb * Dd;                  // 4096
static constexpr int    CBD    = CHUNKS * BD;              // 262144
static constexpr size_t MiB    = 1024 * 1024;

__device__ __forceinline__ float gelu_tanh(float x) {
    float x3 = x * x * x;
    float t  = tanhf(0.7978845608028654f * (x + 0.044715f * x3));
    return 0.5f * x * (1.0f + t);
}
__device__ __forceinline__ float silu(float x) { return x / (1.0f + expf(-x)); }

// async global->LDS, 16 B per lane; lds dest = base + lane*16 (wave-uniform base)
__device__ __forceinline__ void async16(const void* g, void* l) {
    __builtin_amdgcn_global_load_lds(
        (const __attribute__((address_space(1))) unsigned int*)(uintptr_t)g,
        (__attribute__((address_space(3))) unsigned int*)(uintptr_t)l,
        16, 0, 0);
}

// ---------------- MFMA GEMM: C[M,N] = A[M,K](f16) @ Bt[N,K](f16)^T ----------
// EPI: 0 none | 1 bias+gelu | 2 bias | 3 mul-by-existing-C(f16) | 4 silu
template <int EPI, typename TC>
__global__ __launch_bounds__(256) void mgemm_k(const f16* __restrict__ A,
                                               const f16* __restrict__ Bt,
                                               TC* __restrict__ C,
                                               int M, int N, int K,
                                               const float* __restrict__ bias) {
    __shared__ f16 As[128 * 32];   // [row][k] row-major, 32 f16/row
    __shared__ f16 Bs[128 * 32];   // [col][k] row-major
    const int tid  = threadIdx.x;
    const int wave = tid >> 6;
    const int lane = tid & 63;
    const int bm   = blockIdx.y * 128;
    const int bn   = blockIdx.x * 128;
    const int rw   = (wave & 1) * 64;
    const int cw   = (wave >> 1) * 64;

    const f16* gA = A  + (size_t)(bm + wave * 32 + (lane >> 2)) * K + (lane & 3) * 8;
    const f16* gB = Bt + (size_t)(bn + wave * 32 + (lane >> 2)) * K + (lane & 3) * 8;
    f16* lA = As + wave * 1024;
    f16* lB = Bs + wave * 1024;

    f32x4 acc[4][4] = {};

    const int fr = lane & 15;
    const int fk = (lane >> 4) * 8;

    for (int k0 = 0; k0 < K; k0 += 32) {
        __syncthreads();
        async16(gA + k0,          lA);
        async16(gA + 16 * K + k0, lA + 512);
        async16(gB + k0,          lB);
        async16(gB + 16 * K + k0, lB + 512);
        __syncthreads();
        f16x8 af[4], bfr[4];
#pragma unroll
        for (int i = 0; i < 4; ++i)
            af[i] = *(const f16x8*)&As[(rw + i * 16 + fr) * 32 + fk];
#pragma unroll
        for (int j = 0; j < 4; ++j)
            bfr[j] = *(const f16x8*)&Bs[(cw + j * 16 + fr) * 32 + fk];
#pragma unroll
        for (int i = 0; i < 4; ++i)
#pragma unroll
            for (int j = 0; j < 4; ++j)
                acc[i][j] = __builtin_amdgcn_mfma_f32_16x16x32_f16(af[i], bfr[j], acc[i][j], 0, 0, 0);
    }

    // epilogue: C row = (lane>>4)*4 + reg, col = lane&15  (dtype-independent)
    const int er = (lane >> 4) * 4;
    const int ec = lane & 15;
#pragma unroll
    for (int i = 0; i < 4; ++i) {
#pragma unroll
        for (int j = 0; j < 4; ++j) {
            const int col = bn + cw + j * 16 + ec;
#pragma unroll
            for (int r = 0; r < 4; ++r) {
                const size_t row = (size_t)(bm + rw + i * 16 + er + r);
                float o = acc[i][j][r];
                if (EPI == 1 || EPI == 2) o += bias[col];
                if (EPI == 1) o = gelu_tanh(o);
                if (EPI == 4) o = silu(o);
                if (EPI == 3) o *= (float)((const f16*)C)[row * N + col];
                if (sizeof(TC) == 4) ((float*)C)[row * N + col] = o;
                else                 ((f16*)C)[row * N + col] = (f16)o;
            }
        }
    }
}

// ---------------- weight transpose+convert: Wt[n][k] = f16(W[k][n]) ---------
__global__ __launch_bounds__(256) void wtrans_k(const float* __restrict__ W,
                                                f16* __restrict__ Wt,
                                                int K, int N) {
    __shared__ float t[32][33];
    const int n0 = blockIdx.x * 32, k0 = blockIdx.y * 32;
    const int tx = threadIdx.x & 31, ty = threadIdx.x >> 5;   // 8 rows
#pragma unroll
    for (int i = 0; i < 32; i += 8)
        t[ty + i][tx] = W[(size_t)(k0 + ty + i) * N + n0 + tx];
    __syncthreads();
#pragma unroll
    for (int i = 0; i < 32; i += 8)
        Wt[(size_t)(n0 + ty + i) * K + k0 + tx] = (f16)t[tx][ty + i];
}

// ---------------- x fp32 -> fp16 --------------------------------------------
__global__ __launch_bounds__(256) void f2h_k(const float* __restrict__ x,
                                             f16* __restrict__ xh) {
    size_t i = ((size_t)blockIdx.x * 256 + threadIdx.x) * 4;
    float4 v = *(const float4*)&x[i];
    f16x4 s;
    s.x = (f16)v.x; s.y = (f16)v.y; s.z = (f16)v.z; s.w = (f16)v.w;
    *(f16x4*)&xh[i] = s;
}

// ------- a transform: a_c = sigmoid(|a|)*a/|a| (fp16 in place) --------------
__global__ __launch_bounds__(256) void a_transform_k(f16* __restrict__ a2d) {
    int gid = blockIdx.x * 256 + threadIdx.x;   // < M*D
    int j   = gid & 1023;
    int row = gid >> 10;
    size_t i0 = (size_t)row * 2048 + j;
    float ar = (float)a2d[i0], ai = (float)a2d[i0 + 1024];
    float mag = sqrtf(ar * ar + ai * ai);
    float sg  = 1.0f / (1.0f + expf(-mag));
    float re, im;
    if (mag > 1e-30f) { float s = sg / mag; re = ar * s; im = ai * s; }
    else              { re = sg; im = 0.0f; }
    a2d[i0]        = (f16)re;
    a2d[i0 + 1024] = (f16)im;
}

// ---------------- chunked complex scan (fp32 state) -------------------------
__global__ __launch_bounds__(256) void scan_pass1_k(const f16* __restrict__ a2d,
                                                    const f16* __restrict__ kv,
                                                    float4* __restrict__ chunk) {
    int tid = blockIdx.x * 256 + threadIdx.x;    // < CBD
    int d   = tid & 1023;
    int t1  = tid >> 10;
    int b   = t1 & 3;
    int c   = t1 >> 2;
    int t0  = c * CLEN;
    int rbase = b * Ss;
    float Are = 1.0f, Aim = 0.0f, Hre = 0.0f, Him = 0.0f;
    for (int t = t0; t < t0 + CLEN; ++t) {
        int r = rbase + t;
        float are = (float)a2d[(size_t)r * 2048 + d];
        float aim = (float)a2d[(size_t)r * 2048 + 1024 + d];
        float kvv = (float)kv[(size_t)r * 1024 + d];
        float hre = are * Hre - aim * Him + kvv;
        float him = are * Him + aim * Hre;
        Hre = hre; Him = him;
        float pre = are * Are - aim * Aim;
        float pim = are * Aim + aim * Are;
        Are = pre; Aim = pim;
    }
    chunk[tid] = make_float4(Are, Aim, Hre, Him);
}

__global__ __launch_bounds__(256) void scan_pass2_k(const float4* __restrict__ chunk,
                                                    float2* __restrict__ carry,
                                                    float* __restrict__ stats) {
    int tid = blockIdx.x * blockDim.x + threadIdx.x;  // < B*D = 4096
    if (tid < 512) stats[tid] = 0.0f;                 // ws is poisoned: zero gn stats
    float hre = 0.0f, him = 0.0f;
    for (int c = 0; c < CHUNKS; ++c) {
        int task = c * BD + tid;
        float4 ch = chunk[task];
        carry[task] = make_float2(hre, him);
        float nre = ch.x * hre - ch.y * him + ch.z;
        float nim = ch.x * him + ch.y * hre + ch.w;
        hre = nre; him = nim;
    }
}

__global__ __launch_bounds__(256) void scan_pass3_k(const f16* __restrict__ a2d,
                                                    const f16* __restrict__ kv,
                                                    const f16* __restrict__ qb,
                                                    const float2* __restrict__ carry,
                                                    f16* __restrict__ yre,
                                                    float* __restrict__ stats) {
    int tid = blockIdx.x * 256 + threadIdx.x;    // < CBD
    int d   = tid & 1023;
    int t1  = tid >> 10;
    int b   = t1 & 3;
    int c   = t1 >> 2;
    int t0  = c * CLEN;
    int rbase = b * Ss;
    float2 cr = carry[tid];
    float hre = cr.x, him = cr.y;
    float sre = 0.0f, sim = 0.0f, s2 = 0.0f;
    for (int t = t0; t < t0 + CLEN; ++t) {
        int r = rbase + t;
        float are = (float)a2d[(size_t)r * 2048 + d];
        float aim = (float)a2d[(size_t)r * 2048 + 1024 + d];
        float kvv = (float)kv[(size_t)r * 1024 + d];
        float nre = are * hre - aim * him + kvv;
        float nim = are * him + aim * hre;
        hre = nre; him = nim;
        float qv  = (float)qb[(size_t)r * 1024 + d];
        float yr_ = qv * hre;
        float yi_ = qv * him;
        yre[(size_t)r * 1024 + d] = (f16)yr_;
        sre += yr_; sim += yi_; s2 += yr_ * yr_ + yi_ * yi_;
    }
#pragma unroll
    for (int off = 16; off > 0; off >>= 1) {
        sre += __shfl_down(sre, off, 32);
        sim += __shfl_down(sim, off, 32);
        s2  += __shfl_down(s2,  off, 32);
    }
    if ((threadIdx.x & 31) == 0) {
        int idx = (b * 32 + (d >> 5)) * 4;
        atomicAdd(&stats[idx + 0], sre);
        atomicAdd(&stats[idx + 1], sim);
        atomicAdd(&stats[idx + 2], s2);
    }
}

// ---------------- groupnorm (real part) + silu-gate, fp16 in place ----------
__global__ __launch_bounds__(256) void gn_gate_k(f16* __restrict__ y,
                                                 const f16* __restrict__ g,
                                                 const float* __restrict__ stats,
                                                 const float* __restrict__ gn_scale,
                                                 const float* __restrict__ gn_bias) {
    size_t gid = (size_t)blockIdx.x * 256 + threadIdx.x;  // < M*D
    int d   = (int)(gid & 1023);
    int row = (int)(gid >> 10);
    int b   = row >> 12;
    int grp = d >> 5;
    const float* st = &stats[(b * 32 + grp) * 4];
    const float invN = 1.0f / 131072.0f;       // S * (D/G)
    float mre = st[0] * invN;
    float mim = st[1] * invN;
    float var = st[2] * invN - mre * mre - mim * mim;
    float rstd = rsqrtf(var + EPSN);
    float re = ((float)y[gid] - mre) * rstd * gn_scale[d] + gn_bias[d];
    y[gid] = (f16)(re * (float)g[gid]);
}

// ---------------- layernorm over D=1024: out = LN(a + b) --------------------
__device__ __forceinline__ float ldf(const float* p, size_t i) { return p[i]; }
__device__ __forceinline__ float ldf(const f16* p, size_t i)   { return (float)p[i]; }
__device__ __forceinline__ void  stf(float* p, size_t i, float v) { p[i] = v; }
__device__ __forceinline__ void  stf(f16* p, size_t i, float v)   { p[i] = (f16)v; }

__device__ __forceinline__ float block_reduce_sum(float v, float* s4, int tid) {
#pragma unroll
    for (int off = 32; off > 0; off >>= 1) v += __shfl_down(v, off, 64);
    __syncthreads();
    if ((tid & 63) == 0) s4[tid >> 6] = v;
    __syncthreads();
    return s4[0] + s4[1] + s4[2] + s4[3];
}

template <typename TA, typename TB, typename TO>
__global__ __launch_bounds__(256) void ln_k(const TA* __restrict__ a,
                                            const TB* __restrict__ b,
                                            const float* __restrict__ scale,
                                            const float* __restrict__ bias,
                                            TO* __restrict__ out) {
    __shared__ float s4[4];
    int row = blockIdx.x;
    size_t base = (size_t)row * 1024;
    int tid = threadIdx.x;
    float v[4];
    float s = 0.0f;
#pragma unroll
    for (int i = 0; i < 4; ++i) {
        int d = tid + i * 256;
        v[i] = ldf(a, base + d) + ldf(b, base + d);
        s += v[i];
    }
    float mu = block_reduce_sum(s, s4, tid) * (1.0f / 1024.0f);
    float s2 = 0.0f;
#pragma unroll
    for (int i = 0; i < 4; ++i) {
        float dv = v[i] - mu;
        s2 += dv * dv;
    }
    float var = block_reduce_sum(s2, s4, tid) * (1.0f / 1024.0f);
    float rstd = rsqrtf(var + EPSN);
#pragma unroll
    for (int i = 0; i < 4; ++i) {
        int d = tid + i * 256;
        stf(out, base + d, (v[i] - mu) * rstd * scale[d] + bias[d]);
    }
}

// ---------------------------------------------------------------------------
extern "C" void kernel_launch(void* const* d_in, const int* in_sizes, int n_in,
                              void* d_out, int out_size, void* d_ws, size_t ws_size,
                              hipStream_t stream) {
    const float* x        = (const float*)d_in[0];
    const float* Wq       = (const float*)d_in[1];
    const float* Wk       = (const float*)d_in[2];
    const float* Wv       = (const float*)d_in[3];
    const float* Wa       = (const float*)d_in[4];
    const float* Wg       = (const float*)d_in[5];
    const float* Wo       = (const float*)d_in[6];
    const float* gn_scale = (const float*)d_in[7];
    const float* gn_bias  = (const float*)d_in[8];
    const float* ln1_s    = (const float*)d_in[9];
    const float* ln1_b    = (const float*)d_in[10];
    const float* W1       = (const float*)d_in[11];
    const float* b1       = (const float*)d_in[12];
    const float* W2       = (const float*)d_in[13];
    const float* b2       = (const float*)d_in[14];
    const float* ln2_s    = (const float*)d_in[15];
    const float* ln2_b    = (const float*)d_in[16];
    float* out = (float*)d_out;

    char* base = (char*)d_ws;
    f16* W1T = (f16*)(base + 0 * MiB);    // [4096, 1024]
    f16* W2T = (f16*)(base + 8 * MiB);    // [1024, 4096]
    f16* WqT = (f16*)(base + 16 * MiB);   // [1024, 1024]
    f16* WkT = (f16*)(base + 18 * MiB);
    f16* WvT = (f16*)(base + 20 * MiB);
    f16* WgT = (f16*)(base + 22 * MiB);
    f16* WoT = (f16*)(base + 24 * MiB);
    f16* WaT = (f16*)(base + 26 * MiB);   // [2048, 1024]
    float4* chunk = (float4*)(base + 30 * MiB);
    float2* carry = (float2*)(base + 34 * MiB);
    float*  stats = (float*)(base + 36 * MiB);
    f16* xb  = (f16*)(base + 37 * MiB);
    f16* kvb = (f16*)(base + 69 * MiB);
    f16* qb  = (f16*)(base + 101 * MiB);
    f16* gb  = (f16*)(base + 133 * MiB);
    f16* yb  = (f16*)(base + 165 * MiB);  // ends 197 MiB
    // aliases (lifetimes verified):
    f16*   ab = (f16*)d_out;              // [M,2D] fp16 = 64 MiB; dead after pass3
    f16*   yo = qb;                       // Wo out; q dead after pass3
    f16*   x1 = xb;                       // post-ln1; xb dead after projections
    f16*   h1 = kvb;                      // [M,F] f16 = 128 MiB: 69..197 all dead
    float* h2 = (float*)d_out;            // fp32 [M,D]; a dead after pass3

    dim3 blk(256);

    // 0. conversions
    f2h_k<<<Mrows, blk, 0, stream>>>(x, xb);
    wtrans_k<<<dim3(128, 32), blk, 0, stream>>>(W1, W1T, Dd, Ff);
    wtrans_k<<<dim3(32, 128), blk, 0, stream>>>(W2, W2T, Ff, Dd);
    wtrans_k<<<dim3(32, 32),  blk, 0, stream>>>(Wq, WqT, Dd, Dd);
    wtrans_k<<<dim3(32, 32),  blk, 0, stream>>>(Wk, WkT, Dd, Dd);
    wtrans_k<<<dim3(32, 32),  blk, 0, stream>>>(Wv, WvT, Dd, Dd);
    wtrans_k<<<dim3(32, 32),  blk, 0, stream>>>(Wg, WgT, Dd, Dd);
    wtrans_k<<<dim3(32, 32),  blk, 0, stream>>>(Wo, WoT, Dd, Dd);
    wtrans_k<<<dim3(64, 32),  blk, 0, stream>>>(Wa, WaT, Dd, 2 * Dd);

    // 1. input projections
    mgemm_k<0, f16><<<dim3(Dd / 128, Mrows / 128), blk, 0, stream>>>(xb, WqT, qb, Mrows, Dd, Dd, nullptr);
    mgemm_k<0, f16><<<dim3(Dd / 128, Mrows / 128), blk, 0, stream>>>(xb, WkT, kvb, Mrows, Dd, Dd, nullptr);
    mgemm_k<3, f16><<<dim3(Dd / 128, Mrows / 128), blk, 0, stream>>>(xb, WvT, kvb, Mrows, Dd, Dd, nullptr);
    mgemm_k<0, f16><<<dim3(2 * Dd / 128, Mrows / 128), blk, 0, stream>>>(xb, WaT, ab, Mrows, 2 * Dd, Dd, nullptr);
    mgemm_k<4, f16><<<dim3(Dd / 128, Mrows / 128), blk, 0, stream>>>(xb, WgT, gb, Mrows, Dd, Dd, nullptr);

    // 2. a transform (fp16, in place in d_out)
    a_transform_k<<<MD / 256, blk, 0, stream>>>(ab);

    // 3. chunked scan
    scan_pass1_k<<<CBD / 256, blk, 0, stream>>>(ab, kvb, chunk);
    scan_pass2_k<<<BD / 256, blk, 0, stream>>>(chunk, carry, stats);
    scan_pass3_k<<<CBD / 256, blk, 0, stream>>>(ab, kvb, qb, carry, yb, stats);

    // 4. groupnorm + gate (in place on yb)
    gn_gate_k<<<MD / 256, blk, 0, stream>>>(yb, gb, stats, gn_scale, gn_bias);

    // 5. output projection + ln1 (x1 -> xb slot; xb dead after projections)
    mgemm_k<0, f16><<<dim3(Dd / 128, Mrows / 128), blk, 0, stream>>>(yb, WoT, yo, Mrows, Dd, Dd, nullptr);
    ln_k<float, f16, f16><<<Mrows, blk, 0, stream>>>(x, yo, ln1_s, ln1_b, x1);

    // 6. MLP (h1 overlays 69..197 MiB; h2 -> d_out fp32)
    mgemm_k<1, f16  ><<<dim3(Ff / 128, Mrows / 128), blk, 0, stream>>>(x1, W1T, h1, Mrows, Ff, Dd, b1);
    mgemm_k<2, float><<<dim3(Dd / 128, Mrows / 128), blk, 0, stream>>>(h1, W2T, h2, Mrows, Dd, Ff, b2);

    // 7. final layernorm -> out (in place over h2: per-thread read-then-write)
    ln_k<f16, float, float><<<Mrows, blk, 0, stream>>>(x1, h2, ln2_s, ln2_b, out);
}